// Round 16
// baseline (826.187 us; speedup 1.0000x reference)
//
#include <hip/hip_runtime.h>
#include <stdint.h>

typedef __attribute__((ext_vector_type(8))) short short8;
typedef __attribute__((ext_vector_type(4))) float f32x4;

__device__ __forceinline__ unsigned short f2bf(float f) {
  union { float f; uint32_t u; } v; v.f = f;
  uint32_t u = v.u;
  u += 0x7FFF + ((u >> 16) & 1);   // round-to-nearest-even
  return (unsigned short)(u >> 16);
}
__device__ __forceinline__ float bf2f(unsigned short h) {
  union { uint32_t u; float f; } v; v.u = ((uint32_t)h) << 16;
  return v.f;
}

// ---- concat-convert both inputs: temporal -> cols 0:1024, graph -> 1024:2048
__global__ void convcat2_kernel(const float* __restrict__ t,
                                const float* __restrict__ g,
                                unsigned short* __restrict__ out, long half) {
  long i = ((long)blockIdx.x * blockDim.x + threadIdx.x) * 8;
  const float* src;
  int colbase;
  if (i < half) { src = t; colbase = 0; }
  else { i -= half; src = g; colbase = 1024; }
  float4 a = *(const float4*)(src + i);
  float4 b = *(const float4*)(src + i + 4);
  short8 s;
  s[0] = (short)f2bf(a.x); s[1] = (short)f2bf(a.y);
  s[2] = (short)f2bf(a.z); s[3] = (short)f2bf(a.w);
  s[4] = (short)f2bf(b.x); s[5] = (short)f2bf(b.y);
  s[6] = (short)f2bf(b.z); s[7] = (short)f2bf(b.w);
  long row = i >> 10, col = i & 1023;
  *(short8*)(out + row * 2048 + colbase + col) = s;
}

// ---- 4-segment fp32->bf16 convert (segment sizes multiples of 2048) ------
__global__ void multiconv_kernel(const float* __restrict__ s0, unsigned short* d0, long n0,
                                 const float* __restrict__ s1, unsigned short* d1, long n1,
                                 const float* __restrict__ s2, unsigned short* d2, long n2,
                                 const float* __restrict__ s3, unsigned short* d3, long n3) {
  long i = ((long)blockIdx.x * blockDim.x + threadIdx.x) * 8;
  const float* s; unsigned short* d;
  if (i < n0) { s = s0; d = d0; }
  else if ((i -= n0) < n1) { s = s1; d = d1; }
  else if ((i -= n1) < n2) { s = s2; d = d2; }
  else { i -= n2; s = s3; d = d3; }
  float4 a = *(const float4*)(s + i);
  float4 b = *(const float4*)(s + i + 4);
  short8 o;
  o[0] = (short)f2bf(a.x); o[1] = (short)f2bf(a.y);
  o[2] = (short)f2bf(a.z); o[3] = (short)f2bf(a.w);
  o[4] = (short)f2bf(b.x); o[5] = (short)f2bf(b.y);
  o[6] = (short)f2bf(b.z); o[7] = (short)f2bf(b.w);
  *(short8*)(d + i) = o;
}

// convert with per-column scale fold: out[i] = bf16(in[i] * scale[i & 2047])
__global__ void convs_kernel(const float* __restrict__ in,
                             const float* __restrict__ scale,
                             unsigned short* __restrict__ out, int n) {
  long i = ((long)blockIdx.x * blockDim.x + threadIdx.x) * 8;
  if (i >= n) return;
  short8 s;
#pragma unroll
  for (int j = 0; j < 8; ++j)
    s[j] = (short)f2bf(in[i + j] * scale[(i + j) & 2047]);
  *(short8*)(out + i) = s;
}

// transpose-convert pair (z selects); out[C][R] = bf16(in^T)
__global__ void tconv2_kernel(const float* __restrict__ inA,
                              unsigned short* __restrict__ outA,
                              const float* __restrict__ inB,
                              unsigned short* __restrict__ outB, int R, int C) {
  const float* in = blockIdx.z ? inB : inA;
  unsigned short* out = blockIdx.z ? outB : outA;
  __shared__ float tile[32][33];
  int c0 = blockIdx.x * 32, r0 = blockIdx.y * 32;
  int tx = threadIdx.x, ty = threadIdx.y;
#pragma unroll
  for (int i = 0; i < 32; i += 8)
    tile[ty + i][tx] = in[(long)(r0 + ty + i) * C + c0 + tx];
  __syncthreads();
#pragma unroll
  for (int i = 0; i < 32; i += 8)
    out[(long)(c0 + ty + i) * R + r0 + tx] = f2bf(tile[tx][ty + i]);
}

// ---------------- 128x128 compose GEMM (r0-proven, 2-phase) ---------------
enum { CE_PLAIN = 0, CE_WT = 1, CE_ACC = 2 };

template <int CE>
__global__ __launch_bounds__(256)
void compose_kernel(const unsigned short* __restrict__ A, int lda,
                    const unsigned short* __restrict__ W, int ldw,
                    unsigned short* C, int ldc,
                    unsigned short* Ct, long ctoff,
                    int K, int nmt,
                    int pairBase, long aoff, long woff, long coff,
                    int seg2Base, const unsigned short* A2, int lda2,
                    const unsigned short* W2, unsigned short* C2p) {
  constexpr int BK = 32;
  __shared__ unsigned short sA[128 * BK];
  __shared__ unsigned short sB[128 * BK];
  const int tid  = threadIdx.x;
  const int lane = tid & 63;
  const int wave = tid >> 6;
  const int wr = (wave >> 1) * 64;
  const int wc = (wave & 1) * 64;

  int bid = blockIdx.x;
  if (bid >= seg2Base) {
    bid -= seg2Base;
    A = A2; lda = lda2; W = W2; C = C2p;
  } else if (bid >= pairBase) {
    bid -= pairBase;
    A += aoff; W += woff; C += coff; Ct += ctoff;
  }
  const long tileM = (long)(bid % nmt) * 128;
  const long tileN = (long)(bid / nmt) * 128;

  const unsigned short* gA = A + (tileM + (tid >> 2)) * (long)lda + (tid & 3) * 8;
  const unsigned short* gB = W + (tileN + (tid >> 2)) * (long)ldw + (tid & 3) * 8;
  unsigned short* lA = sA + wave * 512;
  unsigned short* lB = sB + wave * 512;

  f32x4 acc[4][4] = {};
  const int fr = lane & 15;
  const int kb = (lane >> 4) * 8;

  for (int k0 = 0; k0 < K; k0 += BK) {
    __builtin_amdgcn_global_load_lds(
        (const __attribute__((address_space(1))) void*)(gA + k0),
        (__attribute__((address_space(3))) void*)(lA), 16, 0, 0);
    __builtin_amdgcn_global_load_lds(
        (const __attribute__((address_space(1))) void*)(gA + k0 + 64 * (long)lda),
        (__attribute__((address_space(3))) void*)(lA + 2048), 16, 0, 0);
    __builtin_amdgcn_global_load_lds(
        (const __attribute__((address_space(1))) void*)(gB + k0),
        (__attribute__((address_space(3))) void*)(lB), 16, 0, 0);
    __builtin_amdgcn_global_load_lds(
        (const __attribute__((address_space(1))) void*)(gB + k0 + 64 * (long)ldw),
        (__attribute__((address_space(3))) void*)(lB + 2048), 16, 0, 0);
    __syncthreads();

    short8 aF[4], bF[4];
#pragma unroll
    for (int m = 0; m < 4; ++m)
      aF[m] = *(const short8*)&sA[(wr + m * 16 + fr) * BK + kb];
#pragma unroll
    for (int n = 0; n < 4; ++n)
      bF[n] = *(const short8*)&sB[(wc + n * 16 + fr) * BK + kb];
#pragma unroll
    for (int m = 0; m < 4; ++m)
#pragma unroll
      for (int n = 0; n < 4; ++n)
        acc[m][n] = __builtin_amdgcn_mfma_f32_16x16x32_bf16(aF[m], bF[n], acc[m][n], 0, 0, 0);
    __syncthreads();
  }

  const int cr = (lane >> 4) * 4;
  const int cc = lane & 15;
#pragma unroll
  for (int m = 0; m < 4; ++m) {
    long r0 = tileM + wr + m * 16 + cr;
#pragma unroll
    for (int n = 0; n < 4; ++n) {
      long c = tileN + wc + n * 16 + cc;
#pragma unroll
      for (int r = 0; r < 4; ++r) {
        long idx = (r0 + r) * (long)ldc + c;
        float v = acc[m][n][r];
        if constexpr (CE == CE_ACC) v += bf2f(C[idx]);
        unsigned short bv = f2bf(v);
        C[idx] = bv;
        if constexpr (CE == CE_WT) Ct[c * 2048 + (r0 + r)] = bv;
      }
    }
  }
}

// ------- 256x256 bf16 GEMM, 4 merged phases (r12-proven schedule) ---------
// EPI_FUSE: B half0 rows from W (Wcross), half1 from W2 (Wgate) — block holds
// cross (frags n=0,1) and logits (n=2,3) for the SAME output cols/rows.
// Epilogue fuses sigmoid-gate + residual, writes PL, and reduces per-row
// (sum, sumsq) partials via shuffle + LDS (smem dead after K-loop).
enum { EPI_BIAS = 0, EPI_LNF32 = 4, EPI_FUSE = 5 };

#define VMW(N) asm volatile("s_waitcnt vmcnt(" #N ")" ::: "memory")
#define SBAR() __builtin_amdgcn_s_barrier()

#define STG(D, OP, HALF, PTR, LD8)                                            \
  { char* lp_ = (char*)smem + ((D)*65536 + (OP)*32768 + (HALF)*16384 + w*2048); \
    __builtin_amdgcn_global_load_lds(                                         \
        (const __attribute__((address_space(1))) void*)(PTR),                 \
        (__attribute__((address_space(3))) void*)lp_, 16, 0, 0);              \
    __builtin_amdgcn_global_load_lds(                                         \
        (const __attribute__((address_space(1))) void*)((PTR) + (LD8)),       \
        (__attribute__((address_space(3))) void*)(lp_ + 1024), 16, 0, 0);     \
    (PTR) += 64; }
#define NOSTG ((void)0)

#define RDA(D, KK) ((KK) ? ((D) ? pA11 : pA01) : ((D) ? pA10 : pA00))
#define RDB(D, KK) ((KK) ? ((D) ? pB11 : pB01) : ((D) ? pB10 : pB00))

template <int EPI, int SWZ>
__global__ __launch_bounds__(512, 2)
void gemm8p_kernel(const unsigned short* __restrict__ A, int lda,
                   const unsigned short* __restrict__ W,
                   const unsigned short* __restrict__ W2b, int ldw,
                   int K, int ldc, int nmt,
                   const float* __restrict__ bias,
                   const float* __restrict__ bias2,
                   const unsigned short* __restrict__ Gp,
                   float2* __restrict__ partials,
                   const float2* __restrict__ stats,
                   void* Cv) {
  __shared__ unsigned short smem[65536];  // 128 KB

  const int tid = threadIdx.x, lane = tid & 63, w = tid >> 6;
  const int wm = w >> 2, wn = w & 3;

  int bid = blockIdx.x;
  int mt, nt;
  if (SWZ) {  // XCD x owns mt [x*8, x*8+8), sweeps all nt
    const int xcd = bid & 7, seq = bid >> 3;
    nt = seq >> 3;
    mt = xcd * 8 + (seq & 7);
  } else {
    mt = bid % nmt;
    nt = bid / nmt;
  }
  const long tileM = (long)mt * 256, tileN = (long)nt * 256;

  const int sRow = w * 16 + (lane >> 3);
  const int sCol = (((lane & 7) ^ ((lane >> 3) & 7)) * 8);
  const unsigned short* pSA0 = A + (tileM + sRow) * (long)lda + sCol;
  const unsigned short* pSA1 = pSA0 + 128 * (long)lda;
  // B halves: FUSE reads half0 from W (rows nt*128..), half1 from W2b.
  const long bRow = (EPI == EPI_FUSE) ? (long)nt * 128 : tileN;
  const unsigned short* pSB0 = W + (bRow + sRow) * (long)ldw + sCol;
  const unsigned short* pSB1 = (EPI == EPI_FUSE)
      ? (W2b + (bRow + sRow) * (long)ldw + sCol)
      : (pSB0 + 128 * (long)ldw);
  const long lda8 = 8 * (long)lda, ldw8 = 8 * (long)ldw;

  const int fr = lane & 15, kc = lane >> 4, l7 = lane & 7;
  const char* pA00 = (const char*)smem + (wm * 16 + fr) * 128 + ((kc) ^ l7) * 16;
  const char* pA01 = (const char*)smem + (wm * 16 + fr) * 128 + ((4 + kc) ^ l7) * 16;
  const char* pA10 = pA00 + 65536;
  const char* pA11 = pA01 + 65536;
  const char* pB00 = (const char*)smem + 32768 + (wn * 16 + fr) * 128 + ((kc) ^ l7) * 16;
  const char* pB01 = (const char*)smem + 32768 + (wn * 16 + fr) * 128 + ((4 + kc) ^ l7) * 16;
  const char* pB10 = pB00 + 65536;
  const char* pB11 = pB01 + 65536;

  f32x4 acc[8][4] = {};
  short8 aH[4][2];
  short8 bqS[2][2][2];  // persists across the MQ pair of a buffer

#define MPHASE(D, MQ, LB, STGX)                                               \
  {                                                                           \
    _Pragma("unroll") for (int mi = 0; mi < 2; ++mi) {                        \
      aH[mi][0] = *(const short8*)(RDA(D, 0) + (MQ)*16384 + mi * 4096);       \
      aH[mi][1] = *(const short8*)(RDA(D, 1) + (MQ)*16384 + mi * 4096);       \
    }                                                                         \
    if (LB) {                                                                 \
      _Pragma("unroll") for (int q = 0; q < 2; ++q)                           \
      _Pragma("unroll") for (int ni = 0; ni < 2; ++ni) {                      \
        bqS[q][ni][0] = *(const short8*)(RDB(D, 0) + q * 16384 + ni * 8192);  \
        bqS[q][ni][1] = *(const short8*)(RDB(D, 1) + q * 16384 + ni * 8192);  \
      }                                                                       \
    }                                                                         \
    _Pragma("unroll") for (int mi = 2; mi < 4; ++mi) {                        \
      aH[mi][0] = *(const short8*)(RDA(D, 0) + (MQ)*16384 + mi * 4096);       \
      aH[mi][1] = *(const short8*)(RDA(D, 1) + (MQ)*16384 + mi * 4096);       \
    }                                                                         \
    STGX;                                                                     \
    __builtin_amdgcn_s_setprio(1);                                            \
    _Pragma("unroll") for (int mi = 0; mi < 4; ++mi)                          \
    _Pragma("unroll") for (int n = 0; n < 4; ++n) {                           \
      acc[(MQ)*4+mi][n] = __builtin_amdgcn_mfma_f32_16x16x32_bf16(            \
          aH[mi][0], bqS[n >> 1][n & 1][0], acc[(MQ)*4+mi][n], 0, 0, 0);      \
      acc[(MQ)*4+mi][n] = __builtin_amdgcn_mfma_f32_16x16x32_bf16(            \
          aH[mi][1], bqS[n >> 1][n & 1][1], acc[(MQ)*4+mi][n], 0, 0, 0);      \
    }                                                                         \
    __builtin_amdgcn_s_setprio(0);                                            \
  }

  // ---- prologue: d0 full + d1 {A0,B0,B1} (d1.A1 staged in MP0 of it 0) ---
  STG(0, 0, 0, pSA0, lda8);
  STG(0, 1, 0, pSB0, ldw8);
  STG(0, 1, 1, pSB1, ldw8);
  STG(0, 0, 1, pSA1, lda8);
  STG(1, 0, 0, pSA0, lda8);
  STG(1, 1, 0, pSB0, ldw8);
  STG(1, 1, 1, pSB1, ldw8);
  VMW(8);
  SBAR();

  const int NIT = K / 128;  // 2 K-tiles (BK=64) per iteration
  for (int it = 0; it < NIT - 1; ++it) {
    MPHASE(0, 0, 1, STG(1, 0, 1, pSA1, lda8));            VMW(8); SBAR();
    MPHASE(0, 1, 0, STG(0, 0, 0, pSA0, lda8);
                    STG(0, 1, 0, pSB0, ldw8);
                    STG(0, 1, 1, pSB1, ldw8));            VMW(8); SBAR();
    MPHASE(1, 0, 1, STG(0, 0, 1, pSA1, lda8));            VMW(8); SBAR();
    MPHASE(1, 1, 0, STG(1, 0, 0, pSA0, lda8);
                    STG(1, 1, 0, pSB0, ldw8);
                    STG(1, 1, 1, pSB1, ldw8));            VMW(8); SBAR();
  }
  {  // peeled drain iteration (stages only d1.A1 for the last odd tile)
    MPHASE(0, 0, 1, STG(1, 0, 1, pSA1, lda8)); VMW(8); SBAR();
    MPHASE(0, 1, 0, NOSTG);                    VMW(2); SBAR();
    MPHASE(1, 0, 1, NOSTG);                    VMW(0); SBAR();
    MPHASE(1, 1, 0, NOSTG);
  }
#undef MPHASE

  // ---- epilogue: C/D layout col = lane&15, row = (lane>>4)*4 + reg --------
  const int cr = (lane >> 4) * 4;
  const int cc = lane & 15;

  if constexpr (EPI == EPI_FUSE) {
    SBAR();  // all waves done with smem; reuse as reduction scratch
    float* sumP  = (float*)smem;          // [256][4]
    float* sumP2 = sumP + 1024;           // [256][4]
#pragma unroll
    for (int m = 0; m < 8; ++m) {
      const int rl0 = (m >> 2) * 128 + (m & 3) * 32 + wm * 16 + cr;
#pragma unroll
      for (int r = 0; r < 4; ++r) {
        long row = tileM + rl0 + r;
        float sA = 0.f, s2A = 0.f;
#pragma unroll
        for (int n = 0; n < 2; ++n) {
          long col = (long)nt * 128 + n * 64 + wn * 16 + cc;
          float cross = acc[m][n][r] + bias[col];
          float logit = acc[m][n + 2][r] + bias2[col];
          float gt = 1.0f / (1.0f + expf(-logit));
          float gv = bf2f(Gp[row * 2048 + col]);
          unsigned short pb = f2bf(gt * gv + (1.0f - gt) * cross + gv);
          ((unsigned short*)Cv)[row * (long)ldc + col] = pb;
          float x = bf2f(pb);
          sA += x; s2A += x * x;
        }
#pragma unroll
        for (int off = 1; off < 16; off <<= 1) {
          sA  += __shfl_xor(sA, off);
          s2A += __shfl_xor(s2A, off);
        }
        if ((lane & 15) == 0) {
          int rl = rl0 + r;
          sumP[rl * 4 + wn]  = sA;
          sumP2[rl * 4 + wn] = s2A;
        }
      }
    }
    SBAR();
    if (tid < 256) {
      float s  = sumP[tid * 4] + sumP[tid * 4 + 1] + sumP[tid * 4 + 2] + sumP[tid * 4 + 3];
      float s2 = sumP2[tid * 4] + sumP2[tid * 4 + 1] + sumP2[tid * 4 + 2] + sumP2[tid * 4 + 3];
      partials[(tileM + tid) * 16 + nt] = make_float2(s, s2);
    }
    return;
  }

#pragma unroll
  for (int m = 0; m < 8; ++m) {
    long rr = tileM + (m >> 2) * 128 + (m & 3) * 32 + wm * 16 + cr;
#pragma unroll
    for (int n = 0; n < 4; ++n) {
      long c = tileN + (n >> 1) * 128 + (n & 1) * 64 + wn * 16 + cc;
      float b1 = bias ? bias[c] : 0.0f;
      float b2 = bias2 ? bias2[c] : 0.0f;
#pragma unroll
      for (int r = 0; r < 4; ++r) {
        long row = rr + r;
        long idx = row * (long)ldc + c;
        float v = acc[m][n][r];
        if constexpr (EPI == EPI_BIAS) {
          ((unsigned short*)Cv)[idx] = f2bf(v + b1 + b2);
        }
        if constexpr (EPI == EPI_LNF32) {
          float2 st = stats[row];  // (mu, rstd)
          ((float*)Cv)[idx] = v * st.y - st.y * st.x * b1 + b2;
        }
      }
    }
  }
}

// ---- reduce per-row partials -> (mean, rstd) -----------------------------
__global__ __launch_bounds__(256) void lnreduce_kernel(
    const float2* __restrict__ partials, float2* __restrict__ stats) {
  int row = blockIdx.x * 256 + threadIdx.x;
  float s = 0.f, s2 = 0.f;
#pragma unroll
  for (int j = 0; j < 16; ++j) {
    float2 p = partials[(long)row * 16 + j];
    s += p.x; s2 += p.y;
  }
  float mean = s * (1.0f / 2048.0f);
  float var  = s2 * (1.0f / 2048.0f) - mean * mean;
  stats[row] = make_float2(mean, rsqrtf(var + 1e-5f));
}

// block-reduce helper: 256 threads, returns total on t==0
__device__ __forceinline__ float blkRed(float s, float* red, int lane, int wave) {
#pragma unroll
  for (int off = 1; off < 64; off <<= 1) s += __shfl_xor(s, off);
  if (lane == 0) red[wave] = s;
  __syncthreads();
  return red[0] + red[1] + red[2] + red[3];
}

// bcV[c] = o1b+o2b + wO1b[c]·bv1 + wO2b[c]·bv2 + Wc1[c]·tp_b + Wc2[c]·gp_b
__global__ __launch_bounds__(256) void biascompP_kernel(
    const unsigned short* __restrict__ wO1b, const unsigned short* __restrict__ wO2b,
    const unsigned short* __restrict__ Wc1, const unsigned short* __restrict__ Wc2,
    const float* __restrict__ bv1, const float* __restrict__ bv2,
    const float* __restrict__ tpb, const float* __restrict__ gpb,
    const float* __restrict__ o1b, const float* __restrict__ o2b,
    float* __restrict__ bcV) {
  __shared__ float red[4];
  int c = blockIdx.x, t = threadIdx.x, lane = t & 63, wave = t >> 6;
  int k = t * 8;
  float s = 0.f;
  short8 a1 = *(const short8*)(wO1b + (long)c * 2048 + k);
  short8 a2 = *(const short8*)(wO2b + (long)c * 2048 + k);
  short8 a3 = *(const short8*)(Wc1 + (long)c * 2048 + k);
  short8 a4 = *(const short8*)(Wc2 + (long)c * 2048 + k);
#pragma unroll
  for (int j = 0; j < 8; ++j)
    s += bf2f((unsigned short)a1[j]) * bv1[k + j]
       + bf2f((unsigned short)a2[j]) * bv2[k + j]
       + bf2f((unsigned short)a3[j]) * tpb[k + j]
       + bf2f((unsigned short)a4[j]) * gpb[k + j];
  float tot = blkRed(s, red, lane, wave);
  if (t == 0) bcV[c] = tot + o1b[c] + o2b[c];
}

// bgateV[n] = gate_b[n] + gw_g[n,:]·gp_b + gw_c[n,:]·bcV   (fp32 gate_w)
__global__ __launch_bounds__(256) void bgateP_kernel(
    const float* __restrict__ gate_w, const float* __restrict__ gate_b,
    const float* __restrict__ gpb, const float* __restrict__ bcV,
    float* __restrict__ bgateV) {
  __shared__ float red[4];
  int n = blockIdx.x, t = threadIdx.x, lane = t & 63, wave = t >> 6;
  const float* row = gate_w + (long)n * 4096;
  float s = 0.f;
  int k = t * 8;
#pragma unroll
  for (int j = 0; j < 8; ++j)
    s += row[k + j] * gpb[k + j] + row[2048 + k + j] * bcV[k + j];
  float tot = blkRed(s, red, lane, wave);
  if (t == 0) bgateV[n] = tot + gate_b[n];
}

// u[n] = rowsum(gamma-folded wLIN); v[n] = ln_beta·lin_w[n,:] + lin_b[n]
__global__ __launch_bounds__(256) void uvP_kernel(
    const unsigned short* __restrict__ wlinp, const float* __restrict__ lin_w,
    const float* __restrict__ ln_beta, const float* __restrict__ lin_b,
    float* __restrict__ uV, float* __restrict__ vV) {
  __shared__ float redu[4], redv[4];
  int n = blockIdx.x, t = threadIdx.x, lane = t & 63, wave = t >> 6;
  int k = t * 8;
  short8 a1 = *(const short8*)(wlinp + (long)n * 2048 + k);
  float u = 0.f, v = 0.f;
#pragma unroll
  for (int j = 0; j < 8; ++j) {
    u += bf2f((unsigned short)a1[j]);
    v += ln_beta[k + j] * lin_w[(long)n * 2048 + k + j];
  }
#pragma unroll
  for (int off = 1; off < 64; off <<= 1) {
    u += __shfl_xor(u, off);
    v += __shfl_xor(v, off);
  }
  if (lane == 0) { redu[wave] = u; redv[wave] = v; }
  __syncthreads();
  if (t == 0) {
    uV[n] = redu[0] + redu[1] + redu[2] + redu[3];
    vV[n] = redv[0] + redv[1] + redv[2] + redv[3] + lin_b[n];
  }
}

// --------------------------------------------------------------------------
extern "C" void kernel_launch(void* const* d_in, const int* in_sizes, int n_in,
                              void* d_out, int out_size, void* d_ws, size_t ws_size,
                              hipStream_t stream) {
  const float* graph    = (const float*)d_in[0];
  const float* temporal = (const float*)d_in[1];
  const float* gp_w  = (const float*)d_in[2];
  const float* gp_b  = (const float*)d_in[3];
  const float* tp_w  = (const float*)d_in[4];
  const float* tp_b  = (const float*)d_in[5];
  const float* in1_w = (const float*)d_in[6];
  const float* in1_b = (const float*)d_in[7];
  const float* out1_w = (const float*)d_in[8];
  const float* out1_b = (const float*)d_in[9];
  const float* in2_w = (const float*)d_in[10];
  const float* in2_b = (const float*)d_in[11];
  const float* out2_w = (const float*)d_in[12];
  const float* out2_b = (const float*)d_in[13];
  const float* gate_w = (const float*)d_in[14];
  const float* gate_b = (const float*)d_in[15];
  const float* ln_g  = (const float*)d_in[16];
  const float* ln_b  = (const float*)d_in[17];
  const float* lin_w = (const float*)d_in[18];
  const float* lin_b = (const float*)d_in[19];

  const int Bm = 16384, F = 2048, GD = 1024;
  const long BF = (long)Bm * F, FF = (long)F * F, FG = (long)F * GD;

  // ---- ws layout (~233 MB) ----
  unsigned short* TG   = (unsigned short*)d_ws;  // [16384][2048] = [t|g]
  unsigned short* Gbuf = TG + BF;                // g
  unsigned short* wLIN = Gbuf + BF;              // gamma-folded lin_w
  unsigned short* wGP  = wLIN + FF;              // [2048][1024]
  unsigned short* Wcg  = wGP + FG;               // [4096][2048] = [Wcross; Wgate]
  unsigned short* Wcross = Wcg;
  unsigned short* Wgate  = Wcg + FF;
  float* bc2V   = (float*)(Wcg + 2 * FF);        // [4096] = [bcV | bgateV]
  float* uV     = bc2V + 2 * F;
  float* vV     = uV + F;
  float2* stats = (float2*)(vV + F);             // [16384]
  float2* partials = stats + Bm;                 // [16384][16]  (2 MB)
  unsigned short* PLn = (unsigned short*)(partials + (long)Bm * 16);  // [16384][2048]

  // ---- d_out scratch (compose transients; ALL dead before final GEMM) ----
  unsigned short* DO      = (unsigned short*)d_out;
  unsigned short* wv1T    = DO;            // [2048][2048]
  unsigned short* wv2T    = wv1T + FF;
  unsigned short* tpT     = wv2T + FF;     // [1024][2048]
  unsigned short* gpT     = tpT + FG;
  unsigned short* Wc1     = gpT + FG;      // [2048][2048]
  unsigned short* Wc2     = Wc1 + FF;
  unsigned short* wO1b    = Wc2 + FF;
  unsigned short* wO2b    = wO1b + FF;
  unsigned short* wGATEb  = wO2b + FF;     // [2048][4096]
  unsigned short* WcrossT = wGATEb + 2 * FF;  // [2048][2048]

  // 1) zero Wgate (C1-seg3 writes g-cols; C3 accumulates full width)
  hipMemsetAsync(Wgate, 0, FF * sizeof(unsigned short), stream);
  // 2) inputs -> TG = [temporal | graph]
  convcat2_kernel<<<dim3((unsigned)(2 * Bm * GD / 8 / 256)), 256, 0, stream>>>(
      temporal, graph, TG, (long)Bm * GD);
  // 3) weight converts (one kernel, 4 segments)
  {
    long ntot = FG + FF + FF + 2 * FF;
    multiconv_kernel<<<dim3((unsigned)(ntot / 8 / 256)), 256, 0, stream>>>(
        gp_w, wGP, FG, out1_w, wO1b, FF, out2_w, wO2b, FF, gate_w, wGATEb, 2 * FF);
  }
  // 4) gamma-folded lin_w
  convs_kernel<<<dim3((unsigned)(FF / 8 / 256)), 256, 0, stream>>>(lin_w, ln_g, wLIN, (int)FF);
  // 5) transposes
  tconv2_kernel<<<dim3(F / 32, F / 32, 2), dim3(32, 8), 0, stream>>>(
      in1_w + 2 * FF, wv1T, in2_w + 2 * FF, wv2T, F, F);
  tconv2_kernel<<<dim3(GD / 32, F / 32, 2), dim3(32, 8), 0, stream>>>(
      tp_w, tpT, gp_w, gpT, F, GD);

  // 6) C1 triple: Wc1 = wO1@wv1 | Wc2 = wO2@wv2 | Wgate[:,1024:] = gw_g@gp_w
  compose_kernel<CE_PLAIN><<<dim3(640), dim3(256), 0, stream>>>(
      wO1b, F, wv1T, F, Wc1, F, nullptr, 0, F, 16,
      256, wO2b - wO1b, wv2T - wv1T, Wc2 - Wc1,
      512, wGATEb, 2 * F, gpT, Wgate + GD);
  // 7) composed cross-bias
  biascompP_kernel<<<dim3(F), dim3(256), 0, stream>>>(
      wO1b, wO2b, Wc1, Wc2, in1_b + 2 * F, in2_b + 2 * F, tp_b, gp_b,
      out1_b, out2_b, bc2V);
  // 8) C2 pair: Wcross = [Wc1@tp_w | Wc2@gp_w] + transposed copy
  compose_kernel<CE_WT><<<dim3(256), dim3(256), 0, stream>>>(
      Wc1, F, tpT, F, Wcross, F, WcrossT, (long)1024 * 2048, F, 16,
      128, Wc2 - Wc1, gpT - tpT, 1024,
      1 << 30, nullptr, 0, nullptr, nullptr);
  // 9) gate bias + LN-fold vectors
  bgateP_kernel<<<dim3(F), dim3(256), 0, stream>>>(gate_w, gate_b, gp_b, bc2V,
                                                   bc2V + F);
  uvP_kernel<<<dim3(F), dim3(256), 0, stream>>>(wLIN, lin_w, ln_b, lin_b, uV, vV);
  // 10) C3: Wgate += gw_c @ Wcross
  compose_kernel<CE_ACC><<<dim3(256), dim3(256), 0, stream>>>(
      wGATEb + F, 2 * F, WcrossT, F, Wgate, F, nullptr, 0, F, 16,
      1 << 30, 0, 0, 0,
      1 << 30, nullptr, 0, nullptr, nullptr);

  dim3 blk(512);
  // g = graph @ gp_w^T + gp_b          (K=1024) -> Gbuf
  gemm8p_kernel<EPI_BIAS, 1><<<dim3(512), blk, 0, stream>>>(
      TG + GD, F, wGP, nullptr, GD, GD, F, 0,
      gp_b, nullptr, nullptr, nullptr, nullptr, Gbuf);
  // fused CL: cross/logits + gate + residual + partial LN sums -> PLn
  gemm8p_kernel<EPI_FUSE, 1><<<dim3(1024), blk, 0, stream>>>(
      TG, F, Wcross, Wgate, F, F, F, 0,
      bc2V, bc2V + F, Gbuf, partials, nullptr, PLn);
  // reduce partials -> stats
  lnreduce_kernel<<<dim3(Bm / 256), dim3(256), 0, stream>>>(partials, stats);
  // out = rstd*(preLN @ wLIN^T) - rstd*mu*u + v   (K=2048, fp32) -> d_out
  gemm8p_kernel<EPI_LNF32, 1><<<dim3(512), blk, 0, stream>>>(
      PLn, F, wLIN, nullptr, F, F, F, 0,
      uV, vV, nullptr, nullptr, stats, (void*)d_out);
}

// Round 17
// 780.878 us; speedup vs baseline: 1.0580x; 1.0580x over previous
//
#include <hip/hip_runtime.h>
#include <stdint.h>

typedef __attribute__((ext_vector_type(8))) short short8;
typedef __attribute__((ext_vector_type(4))) float f32x4;

__device__ __forceinline__ unsigned short f2bf(float f) {
  union { float f; uint32_t u; } v; v.f = f;
  uint32_t u = v.u;
  u += 0x7FFF + ((u >> 16) & 1);   // round-to-nearest-even
  return (unsigned short)(u >> 16);
}
__device__ __forceinline__ float bf2f(unsigned short h) {
  union { uint32_t u; float f; } v; v.u = ((uint32_t)h) << 16;
  return v.f;
}

// ---- concat-convert both inputs: temporal -> cols 0:1024, graph -> 1024:2048
__global__ void convcat2_kernel(const float* __restrict__ t,
                                const float* __restrict__ g,
                                unsigned short* __restrict__ out, long half) {
  long i = ((long)blockIdx.x * blockDim.x + threadIdx.x) * 8;
  const float* src;
  int colbase;
  if (i < half) { src = t; colbase = 0; }
  else { i -= half; src = g; colbase = 1024; }
  float4 a = *(const float4*)(src + i);
  float4 b = *(const float4*)(src + i + 4);
  short8 s;
  s[0] = (short)f2bf(a.x); s[1] = (short)f2bf(a.y);
  s[2] = (short)f2bf(a.z); s[3] = (short)f2bf(a.w);
  s[4] = (short)f2bf(b.x); s[5] = (short)f2bf(b.y);
  s[6] = (short)f2bf(b.z); s[7] = (short)f2bf(b.w);
  long row = i >> 10, col = i & 1023;
  *(short8*)(out + row * 2048 + colbase + col) = s;
}

// ---- 4-segment fp32->bf16 convert (segment sizes multiples of 2048) ------
__global__ void multiconv_kernel(const float* __restrict__ s0, unsigned short* d0, long n0,
                                 const float* __restrict__ s1, unsigned short* d1, long n1,
                                 const float* __restrict__ s2, unsigned short* d2, long n2,
                                 const float* __restrict__ s3, unsigned short* d3, long n3) {
  long i = ((long)blockIdx.x * blockDim.x + threadIdx.x) * 8;
  const float* s; unsigned short* d;
  if (i < n0) { s = s0; d = d0; }
  else if ((i -= n0) < n1) { s = s1; d = d1; }
  else if ((i -= n1) < n2) { s = s2; d = d2; }
  else { i -= n2; s = s3; d = d3; }
  float4 a = *(const float4*)(s + i);
  float4 b = *(const float4*)(s + i + 4);
  short8 o;
  o[0] = (short)f2bf(a.x); o[1] = (short)f2bf(a.y);
  o[2] = (short)f2bf(a.z); o[3] = (short)f2bf(a.w);
  o[4] = (short)f2bf(b.x); o[5] = (short)f2bf(b.y);
  o[6] = (short)f2bf(b.z); o[7] = (short)f2bf(b.w);
  *(short8*)(d + i) = o;
}

// convert with per-column scale fold: out[i] = bf16(in[i] * scale[i & 2047])
__global__ void convs_kernel(const float* __restrict__ in,
                             const float* __restrict__ scale,
                             unsigned short* __restrict__ out, int n) {
  long i = ((long)blockIdx.x * blockDim.x + threadIdx.x) * 8;
  if (i >= n) return;
  short8 s;
#pragma unroll
  for (int j = 0; j < 8; ++j)
    s[j] = (short)f2bf(in[i + j] * scale[(i + j) & 2047]);
  *(short8*)(out + i) = s;
}

// transpose-convert pair (z selects); out[C][R] = bf16(in^T)
__global__ void tconv2_kernel(const float* __restrict__ inA,
                              unsigned short* __restrict__ outA,
                              const float* __restrict__ inB,
                              unsigned short* __restrict__ outB, int R, int C) {
  const float* in = blockIdx.z ? inB : inA;
  unsigned short* out = blockIdx.z ? outB : outA;
  __shared__ float tile[32][33];
  int c0 = blockIdx.x * 32, r0 = blockIdx.y * 32;
  int tx = threadIdx.x, ty = threadIdx.y;
#pragma unroll
  for (int i = 0; i < 32; i += 8)
    tile[ty + i][tx] = in[(long)(r0 + ty + i) * C + c0 + tx];
  __syncthreads();
#pragma unroll
  for (int i = 0; i < 32; i += 8)
    out[(long)(c0 + ty + i) * R + r0 + tx] = f2bf(tile[tx][ty + i]);
}

// ---------------- 128x128 compose GEMM (r0-proven, 2-phase) ---------------
enum { CE_PLAIN = 0, CE_WT = 1, CE_ACC = 2 };

template <int CE>
__global__ __launch_bounds__(256)
void compose_kernel(const unsigned short* __restrict__ A, int lda,
                    const unsigned short* __restrict__ W, int ldw,
                    unsigned short* C, int ldc,
                    unsigned short* Ct, long ctoff,
                    int K, int nmt,
                    int pairBase, long aoff, long woff, long coff,
                    int seg2Base, const unsigned short* A2, int lda2,
                    const unsigned short* W2, unsigned short* C2p) {
  constexpr int BK = 32;
  __shared__ unsigned short sA[128 * BK];
  __shared__ unsigned short sB[128 * BK];
  const int tid  = threadIdx.x;
  const int lane = tid & 63;
  const int wave = tid >> 6;
  const int wr = (wave >> 1) * 64;
  const int wc = (wave & 1) * 64;

  int bid = blockIdx.x;
  if (bid >= seg2Base) {
    bid -= seg2Base;
    A = A2; lda = lda2; W = W2; C = C2p;
  } else if (bid >= pairBase) {
    bid -= pairBase;
    A += aoff; W += woff; C += coff; Ct += ctoff;
  }
  const long tileM = (long)(bid % nmt) * 128;
  const long tileN = (long)(bid / nmt) * 128;

  const unsigned short* gA = A + (tileM + (tid >> 2)) * (long)lda + (tid & 3) * 8;
  const unsigned short* gB = W + (tileN + (tid >> 2)) * (long)ldw + (tid & 3) * 8;
  unsigned short* lA = sA + wave * 512;
  unsigned short* lB = sB + wave * 512;

  f32x4 acc[4][4] = {};
  const int fr = lane & 15;
  const int kb = (lane >> 4) * 8;

  for (int k0 = 0; k0 < K; k0 += BK) {
    __builtin_amdgcn_global_load_lds(
        (const __attribute__((address_space(1))) void*)(gA + k0),
        (__attribute__((address_space(3))) void*)(lA), 16, 0, 0);
    __builtin_amdgcn_global_load_lds(
        (const __attribute__((address_space(1))) void*)(gA + k0 + 64 * (long)lda),
        (__attribute__((address_space(3))) void*)(lA + 2048), 16, 0, 0);
    __builtin_amdgcn_global_load_lds(
        (const __attribute__((address_space(1))) void*)(gB + k0),
        (__attribute__((address_space(3))) void*)(lB), 16, 0, 0);
    __builtin_amdgcn_global_load_lds(
        (const __attribute__((address_space(1))) void*)(gB + k0 + 64 * (long)ldw),
        (__attribute__((address_space(3))) void*)(lB + 2048), 16, 0, 0);
    __syncthreads();

    short8 aF[4], bF[4];
#pragma unroll
    for (int m = 0; m < 4; ++m)
      aF[m] = *(const short8*)&sA[(wr + m * 16 + fr) * BK + kb];
#pragma unroll
    for (int n = 0; n < 4; ++n)
      bF[n] = *(const short8*)&sB[(wc + n * 16 + fr) * BK + kb];
#pragma unroll
    for (int m = 0; m < 4; ++m)
#pragma unroll
      for (int n = 0; n < 4; ++n)
        acc[m][n] = __builtin_amdgcn_mfma_f32_16x16x32_bf16(aF[m], bF[n], acc[m][n], 0, 0, 0);
    __syncthreads();
  }

  const int cr = (lane >> 4) * 4;
  const int cc = lane & 15;
#pragma unroll
  for (int m = 0; m < 4; ++m) {
    long r0 = tileM + wr + m * 16 + cr;
#pragma unroll
    for (int n = 0; n < 4; ++n) {
      long c = tileN + wc + n * 16 + cc;
#pragma unroll
      for (int r = 0; r < 4; ++r) {
        long idx = (r0 + r) * (long)ldc + c;
        float v = acc[m][n][r];
        if constexpr (CE == CE_ACC) v += bf2f(C[idx]);
        unsigned short bv = f2bf(v);
        C[idx] = bv;
        if constexpr (CE == CE_WT) Ct[c * 2048 + (r0 + r)] = bv;
      }
    }
  }
}

// ------- 256x256 bf16 GEMM, 4 merged phases (r12-proven, 259 us CL) -------
enum { EPI_BIAS = 0, EPI_LNF32 = 4 };

#define VMW(N) asm volatile("s_waitcnt vmcnt(" #N ")" ::: "memory")
#define SBAR() __builtin_amdgcn_s_barrier()

#define STG(D, OP, HALF, PTR, LD8)                                            \
  { char* lp_ = (char*)smem + ((D)*65536 + (OP)*32768 + (HALF)*16384 + w*2048); \
    __builtin_amdgcn_global_load_lds(                                         \
        (const __attribute__((address_space(1))) void*)(PTR),                 \
        (__attribute__((address_space(3))) void*)lp_, 16, 0, 0);              \
    __builtin_amdgcn_global_load_lds(                                         \
        (const __attribute__((address_space(1))) void*)((PTR) + (LD8)),       \
        (__attribute__((address_space(3))) void*)(lp_ + 1024), 16, 0, 0);     \
    (PTR) += 64; }
#define NOSTG ((void)0)

#define RDA(D, KK) ((KK) ? ((D) ? pA11 : pA01) : ((D) ? pA10 : pA00))
#define RDB(D, KK) ((KK) ? ((D) ? pB11 : pB01) : ((D) ? pB10 : pB00))

template <int EPI, int SWZ>
__global__ __launch_bounds__(512, 2)
void gemm8p_kernel(const unsigned short* __restrict__ A, int lda,
                   const unsigned short* __restrict__ W, int ldw,
                   int K, int ldc, int nmt,
                   const float* __restrict__ bias,
                   const float* __restrict__ bias2,
                   const float2* __restrict__ stats,
                   void* Cv) {
  __shared__ unsigned short smem[65536];  // 128 KB

  const int tid = threadIdx.x, lane = tid & 63, w = tid >> 6;
  const int wm = w >> 2, wn = w & 3;

  int bid = blockIdx.x;
  int mt, nt;
  if (SWZ) {  // XCD x owns mt [x*8, x*8+8), sweeps all nt
    const int xcd = bid & 7, seq = bid >> 3;
    nt = seq >> 3;
    mt = xcd * 8 + (seq & 7);
  } else {
    mt = bid % nmt;
    nt = bid / nmt;
  }
  const long tileM = (long)mt * 256, tileN = (long)nt * 256;

  const int sRow = w * 16 + (lane >> 3);
  const int sCol = (((lane & 7) ^ ((lane >> 3) & 7)) * 8);
  const unsigned short* pSA0 = A + (tileM + sRow) * (long)lda + sCol;
  const unsigned short* pSA1 = pSA0 + 128 * (long)lda;
  const unsigned short* pSB0 = W + (tileN + sRow) * (long)ldw + sCol;
  const unsigned short* pSB1 = pSB0 + 128 * (long)ldw;
  const long lda8 = 8 * (long)lda, ldw8 = 8 * (long)ldw;

  const int fr = lane & 15, kc = lane >> 4, l7 = lane & 7;
  const char* pA00 = (const char*)smem + (wm * 16 + fr) * 128 + ((kc) ^ l7) * 16;
  const char* pA01 = (const char*)smem + (wm * 16 + fr) * 128 + ((4 + kc) ^ l7) * 16;
  const char* pA10 = pA00 + 65536;
  const char* pA11 = pA01 + 65536;
  const char* pB00 = (const char*)smem + 32768 + (wn * 16 + fr) * 128 + ((kc) ^ l7) * 16;
  const char* pB01 = (const char*)smem + 32768 + (wn * 16 + fr) * 128 + ((4 + kc) ^ l7) * 16;
  const char* pB10 = pB00 + 65536;
  const char* pB11 = pB01 + 65536;

  f32x4 acc[8][4] = {};
  short8 aH[4][2];
  short8 bqS[2][2][2];  // persists across the MQ pair of a buffer

#define MPHASE(D, MQ, LB, STGX)                                               \
  {                                                                           \
    _Pragma("unroll") for (int mi = 0; mi < 2; ++mi) {                        \
      aH[mi][0] = *(const short8*)(RDA(D, 0) + (MQ)*16384 + mi * 4096);       \
      aH[mi][1] = *(const short8*)(RDA(D, 1) + (MQ)*16384 + mi * 4096);       \
    }                                                                         \
    if (LB) {                                                                 \
      _Pragma("unroll") for (int q = 0; q < 2; ++q)                           \
      _Pragma("unroll") for (int ni = 0; ni < 2; ++ni) {                      \
        bqS[q][ni][0] = *(const short8*)(RDB(D, 0) + q * 16384 + ni * 8192);  \
        bqS[q][ni][1] = *(const short8*)(RDB(D, 1) + q * 16384 + ni * 8192);  \
      }                                                                       \
    }                                                                         \
    _Pragma("unroll") for (int mi = 2; mi < 4; ++mi) {                        \
      aH[mi][0] = *(const short8*)(RDA(D, 0) + (MQ)*16384 + mi * 4096);       \
      aH[mi][1] = *(const short8*)(RDA(D, 1) + (MQ)*16384 + mi * 4096);       \
    }                                                                         \
    STGX;                                                                     \
    __builtin_amdgcn_s_setprio(1);                                            \
    _Pragma("unroll") for (int mi = 0; mi < 4; ++mi)                          \
    _Pragma("unroll") for (int n = 0; n < 4; ++n) {                           \
      acc[(MQ)*4+mi][n] = __builtin_amdgcn_mfma_f32_16x16x32_bf16(            \
          aH[mi][0], bqS[n >> 1][n & 1][0], acc[(MQ)*4+mi][n], 0, 0, 0);      \
      acc[(MQ)*4+mi][n] = __builtin_amdgcn_mfma_f32_16x16x32_bf16(            \
          aH[mi][1], bqS[n >> 1][n & 1][1], acc[(MQ)*4+mi][n], 0, 0, 0);      \
    }                                                                         \
    __builtin_amdgcn_s_setprio(0);                                            \
  }

  // ---- prologue: d0 full + d1 {A0,B0,B1} (d1.A1 staged in MP0 of it 0) ---
  STG(0, 0, 0, pSA0, lda8);
  STG(0, 1, 0, pSB0, ldw8);
  STG(0, 1, 1, pSB1, ldw8);
  STG(0, 0, 1, pSA1, lda8);
  STG(1, 0, 0, pSA0, lda8);
  STG(1, 1, 0, pSB0, ldw8);
  STG(1, 1, 1, pSB1, ldw8);
  VMW(8);
  SBAR();

  const int NIT = K / 128;  // 2 K-tiles (BK=64) per iteration
  for (int it = 0; it < NIT - 1; ++it) {
    MPHASE(0, 0, 1, STG(1, 0, 1, pSA1, lda8));            VMW(8); SBAR();
    MPHASE(0, 1, 0, STG(0, 0, 0, pSA0, lda8);
                    STG(0, 1, 0, pSB0, ldw8);
                    STG(0, 1, 1, pSB1, ldw8));            VMW(8); SBAR();
    MPHASE(1, 0, 1, STG(0, 0, 1, pSA1, lda8));            VMW(8); SBAR();
    MPHASE(1, 1, 0, STG(1, 0, 0, pSA0, lda8);
                    STG(1, 1, 0, pSB0, ldw8);
                    STG(1, 1, 1, pSB1, ldw8));            VMW(8); SBAR();
  }
  {  // peeled drain iteration (stages only d1.A1 for the last odd tile)
    MPHASE(0, 0, 1, STG(1, 0, 1, pSA1, lda8)); VMW(8); SBAR();
    MPHASE(0, 1, 0, NOSTG);                    VMW(2); SBAR();
    MPHASE(1, 0, 1, NOSTG);                    VMW(0); SBAR();
    MPHASE(1, 1, 0, NOSTG);
  }
#undef MPHASE

  // ---- epilogue: C/D layout col = lane&15, row = (lane>>4)*4 + reg --------
  const int cr = (lane >> 4) * 4;
  const int cc = lane & 15;
#pragma unroll
  for (int m = 0; m < 8; ++m) {
    long rr = tileM + (m >> 2) * 128 + (m & 3) * 32 + wm * 16 + cr;
#pragma unroll
    for (int n = 0; n < 4; ++n) {
      long c = tileN + (n >> 1) * 128 + (n & 1) * 64 + wn * 16 + cc;
      float b1 = bias ? bias[c] : 0.0f;
      float b2 = bias2 ? bias2[c] : 0.0f;
#pragma unroll
      for (int r = 0; r < 4; ++r) {
        long row = rr + r;
        long idx = row * (long)ldc + c;
        float v = acc[m][n][r];
        if constexpr (EPI == EPI_BIAS) {
          ((unsigned short*)Cv)[idx] = f2bf(v + b1 + b2);
        }
        if constexpr (EPI == EPI_LNF32) {
          float2 st = stats[row];  // (mu, rstd)
          ((float*)Cv)[idx] = v * st.y - st.y * st.x * b1 + b2;
        }
      }
    }
  }
}

// ---- fuse gate + residual + LN stats, streaming, one row per block -------
__global__ __launch_bounds__(256) void fusestats_kernel(
    const unsigned short* __restrict__ CL, const unsigned short* __restrict__ G,
    unsigned short* __restrict__ PL, float2* __restrict__ stats) {
  const int row = blockIdx.x;
  const int t = threadIdx.x, lane = t & 63, wave = t >> 6;
  short8 xc = *(const short8*)&CL[(long)row * 4096 + t * 8];
  short8 xl = *(const short8*)&CL[(long)row * 4096 + 2048 + t * 8];
  short8 xg = *(const short8*)&G[(long)row * 2048 + t * 8];
  short8 o8;
  float s = 0.f, s2 = 0.f;
#pragma unroll
  for (int j = 0; j < 8; ++j) {
    float cv = bf2f((unsigned short)xc[j]);
    float lv = bf2f((unsigned short)xl[j]);
    float gv = bf2f((unsigned short)xg[j]);
    float gt = 1.0f / (1.0f + expf(-lv));
    unsigned short pb = f2bf(gt * gv + (1.0f - gt) * cv + gv);
    o8[j] = (short)pb;
    float x = bf2f(pb);
    s += x; s2 += x * x;
  }
  *(short8*)(PL + (long)row * 2048 + t * 8) = o8;
#pragma unroll
  for (int off = 1; off < 64; off <<= 1) {
    s  += __shfl_xor(s, off);
    s2 += __shfl_xor(s2, off);
  }
  __shared__ float red[8];
  if (lane == 0) { red[wave] = s; red[4 + wave] = s2; }
  __syncthreads();
  if (t == 0) {
    float ts  = red[0] + red[1] + red[2] + red[3];
    float ts2 = red[4] + red[5] + red[6] + red[7];
    float mean = ts * (1.0f / 2048.0f);
    float var  = ts2 * (1.0f / 2048.0f) - mean * mean;
    stats[row] = make_float2(mean, rsqrtf(var + 1e-5f));
  }
}

// block-reduce helper: 256 threads, returns total on t==0
__device__ __forceinline__ float blkRed(float s, float* red, int lane, int wave) {
#pragma unroll
  for (int off = 1; off < 64; off <<= 1) s += __shfl_xor(s, off);
  if (lane == 0) red[wave] = s;
  __syncthreads();
  return red[0] + red[1] + red[2] + red[3];
}

// bcV[c] = o1b+o2b + wO1b[c]·bv1 + wO2b[c]·bv2 + Wc1[c]·tp_b + Wc2[c]·gp_b
__global__ __launch_bounds__(256) void biascompP_kernel(
    const unsigned short* __restrict__ wO1b, const unsigned short* __restrict__ wO2b,
    const unsigned short* __restrict__ Wc1, const unsigned short* __restrict__ Wc2,
    const float* __restrict__ bv1, const float* __restrict__ bv2,
    const float* __restrict__ tpb, const float* __restrict__ gpb,
    const float* __restrict__ o1b, const float* __restrict__ o2b,
    float* __restrict__ bcV) {
  __shared__ float red[4];
  int c = blockIdx.x, t = threadIdx.x, lane = t & 63, wave = t >> 6;
  int k = t * 8;
  float s = 0.f;
  short8 a1 = *(const short8*)(wO1b + (long)c * 2048 + k);
  short8 a2 = *(const short8*)(wO2b + (long)c * 2048 + k);
  short8 a3 = *(const short8*)(Wc1 + (long)c * 2048 + k);
  short8 a4 = *(const short8*)(Wc2 + (long)c * 2048 + k);
#pragma unroll
  for (int j = 0; j < 8; ++j)
    s += bf2f((unsigned short)a1[j]) * bv1[k + j]
       + bf2f((unsigned short)a2[j]) * bv2[k + j]
       + bf2f((unsigned short)a3[j]) * tpb[k + j]
       + bf2f((unsigned short)a4[j]) * gpb[k + j];
  float tot = blkRed(s, red, lane, wave);
  if (t == 0) bcV[c] = tot + o1b[c] + o2b[c];
}

// bgateV[n] = gate_b[n] + gw_g[n,:]·gp_b + gw_c[n,:]·bcV   (fp32 gate_w)
__global__ __launch_bounds__(256) void bgateP_kernel(
    const float* __restrict__ gate_w, const float* __restrict__ gate_b,
    const float* __restrict__ gpb, const float* __restrict__ bcV,
    float* __restrict__ bgateV) {
  __shared__ float red[4];
  int n = blockIdx.x, t = threadIdx.x, lane = t & 63, wave = t >> 6;
  const float* row = gate_w + (long)n * 4096;
  float s = 0.f;
  int k = t * 8;
#pragma unroll
  for (int j = 0; j < 8; ++j)
    s += row[k + j] * gpb[k + j] + row[2048 + k + j] * bcV[k + j];
  float tot = blkRed(s, red, lane, wave);
  if (t == 0) bgateV[n] = tot + gate_b[n];
}

// u[n] = rowsum(gamma-folded wLIN); v[n] = ln_beta·lin_w[n,:] + lin_b[n]
__global__ __launch_bounds__(256) void uvP_kernel(
    const unsigned short* __restrict__ wlinp, const float* __restrict__ lin_w,
    const float* __restrict__ ln_beta, const float* __restrict__ lin_b,
    float* __restrict__ uV, float* __restrict__ vV) {
  __shared__ float redu[4], redv[4];
  int n = blockIdx.x, t = threadIdx.x, lane = t & 63, wave = t >> 6;
  int k = t * 8;
  short8 a1 = *(const short8*)(wlinp + (long)n * 2048 + k);
  float u = 0.f, v = 0.f;
#pragma unroll
  for (int j = 0; j < 8; ++j) {
    u += bf2f((unsigned short)a1[j]);
    v += ln_beta[k + j] * lin_w[(long)n * 2048 + k + j];
  }
#pragma unroll
  for (int off = 1; off < 64; off <<= 1) {
    u += __shfl_xor(u, off);
    v += __shfl_xor(v, off);
  }
  if (lane == 0) { redu[wave] = u; redv[wave] = v; }
  __syncthreads();
  if (t == 0) {
    uV[n] = redu[0] + redu[1] + redu[2] + redu[3];
    vV[n] = redv[0] + redv[1] + redv[2] + redv[3] + lin_b[n];
  }
}

// --------------------------------------------------------------------------
extern "C" void kernel_launch(void* const* d_in, const int* in_sizes, int n_in,
                              void* d_out, int out_size, void* d_ws, size_t ws_size,
                              hipStream_t stream) {
  const float* graph    = (const float*)d_in[0];
  const float* temporal = (const float*)d_in[1];
  const float* gp_w  = (const float*)d_in[2];
  const float* gp_b  = (const float*)d_in[3];
  const float* tp_w  = (const float*)d_in[4];
  const float* tp_b  = (const float*)d_in[5];
  const float* in1_w = (const float*)d_in[6];
  const float* in1_b = (const float*)d_in[7];
  const float* out1_w = (const float*)d_in[8];
  const float* out1_b = (const float*)d_in[9];
  const float* in2_w = (const float*)d_in[10];
  const float* in2_b = (const float*)d_in[11];
  const float* out2_w = (const float*)d_in[12];
  const float* out2_b = (const float*)d_in[13];
  const float* gate_w = (const float*)d_in[14];
  const float* gate_b = (const float*)d_in[15];
  const float* ln_g  = (const float*)d_in[16];
  const float* ln_b  = (const float*)d_in[17];
  const float* lin_w = (const float*)d_in[18];
  const float* lin_b = (const float*)d_in[19];

  const int Bm = 16384, F = 2048, GD = 1024;
  const long BF = (long)Bm * F, FF = (long)F * F, FG = (long)F * GD;

  // ---- ws layout (~164 MB) ----
  unsigned short* TG   = (unsigned short*)d_ws;  // [16384][2048]=[t|g]; later preLN
  unsigned short* PL   = TG;                     // preLN overwrites TG (dead)
  unsigned short* Gbuf = TG + BF;                // g
  unsigned short* wLIN = Gbuf + BF;              // gamma-folded lin_w
  unsigned short* wGP  = wLIN + FF;              // [2048][1024]
  unsigned short* Wcg  = wGP + FG;               // [4096][2048] = [Wcross; Wgate]
  unsigned short* Wcross = Wcg;
  unsigned short* Wgate  = Wcg + FF;
  float* bc2V   = (float*)(Wcg + 2 * FF);        // [4096] = [bcV | bgateV]
  float* uV     = bc2V + 2 * F;
  float* vV     = uV + F;
  float2* stats = (float2*)(vV + F);             // 16384 float2

  // ---- d_out scratch (compose transients; ALL dead before CL GEMM) ----
  unsigned short* DO      = (unsigned short*)d_out;
  unsigned short* wv1T    = DO;            // [2048][2048]
  unsigned short* wv2T    = wv1T + FF;
  unsigned short* tpT     = wv2T + FF;     // [1024][2048]
  unsigned short* gpT     = tpT + FG;
  unsigned short* Wc1     = gpT + FG;      // [2048][2048]
  unsigned short* Wc2     = Wc1 + FF;
  unsigned short* wO1b    = Wc2 + FF;
  unsigned short* wO2b    = wO1b + FF;
  unsigned short* wGATEb  = wO2b + FF;     // [2048][4096]
  unsigned short* WcrossT = wGATEb + 2 * FF;  // [2048][2048]
  unsigned short* CL      = DO;            // [16384][4096] — overwrites all above

  // 1) zero Wgate (C1-seg3 writes g-cols; C3 accumulates full width)
  hipMemsetAsync(Wgate, 0, FF * sizeof(unsigned short), stream);
  // 2) inputs -> TG = [temporal | graph]
  convcat2_kernel<<<dim3((unsigned)(2 * Bm * GD / 8 / 256)), 256, 0, stream>>>(
      temporal, graph, TG, (long)Bm * GD);
  // 3) weight converts (one kernel, 4 segments)
  {
    long ntot = FG + FF + FF + 2 * FF;
    multiconv_kernel<<<dim3((unsigned)(ntot / 8 / 256)), 256, 0, stream>>>(
        gp_w, wGP, FG, out1_w, wO1b, FF, out2_w, wO2b, FF, gate_w, wGATEb, 2 * FF);
  }
  // 4) gamma-folded lin_w
  convs_kernel<<<dim3((unsigned)(FF / 8 / 256)), 256, 0, stream>>>(lin_w, ln_g, wLIN, (int)FF);
  // 5) transposes (two paired dispatches)
  tconv2_kernel<<<dim3(F / 32, F / 32, 2), dim3(32, 8), 0, stream>>>(
      in1_w + 2 * FF, wv1T, in2_w + 2 * FF, wv2T, F, F);
  tconv2_kernel<<<dim3(GD / 32, F / 32, 2), dim3(32, 8), 0, stream>>>(
      tp_w, tpT, gp_w, gpT, F, GD);

  // 6) C1 triple (640 blocks): Wc1 = wO1@wv1 | Wc2 = wO2@wv2 | Wgate[:,1024:] = gw_g@gp_w
  compose_kernel<CE_PLAIN><<<dim3(640), dim3(256), 0, stream>>>(
      wO1b, F, wv1T, F, Wc1, F, nullptr, 0, F, 16,
      256, wO2b - wO1b, wv2T - wv1T, Wc2 - Wc1,
      512, wGATEb, 2 * F, gpT, Wgate + GD);
  // 7) composed cross-bias (needs Wc1/Wc2)
  biascompP_kernel<<<dim3(F), dim3(256), 0, stream>>>(
      wO1b, wO2b, Wc1, Wc2, in1_b + 2 * F, in2_b + 2 * F, tp_b, gp_b,
      out1_b, out2_b, bc2V);
  // 8) C2 pair: Wcross = [Wc1@tp_w | Wc2@gp_w] + transposed copy
  compose_kernel<CE_WT><<<dim3(256), dim3(256), 0, stream>>>(
      Wc1, F, tpT, F, Wcross, F, WcrossT, (long)1024 * 2048, F, 16,
      128, Wc2 - Wc1, gpT - tpT, 1024,
      1 << 30, nullptr, 0, nullptr, nullptr);
  // 9) gate bias + LN-fold vectors
  bgateP_kernel<<<dim3(F), dim3(256), 0, stream>>>(gate_w, gate_b, gp_b, bc2V,
                                                   bc2V + F);
  uvP_kernel<<<dim3(F), dim3(256), 0, stream>>>(wLIN, lin_w, ln_b, lin_b, uV, vV);
  // 10) C3: Wgate += gw_c @ Wcross
  compose_kernel<CE_ACC><<<dim3(256), dim3(256), 0, stream>>>(
      wGATEb + F, 2 * F, WcrossT, F, Wgate, F, nullptr, 0, F, 16,
      1 << 30, 0, 0, 0,
      1 << 30, nullptr, 0, nullptr, nullptr);

  dim3 blk(512);
  // g = graph @ gp_w^T + gp_b          (K=1024) -> Gbuf
  gemm8p_kernel<EPI_BIAS, 1><<<dim3(512), blk, 0, stream>>>(
      TG + GD, F, wGP, GD, GD, F, 0,
      gp_b, nullptr, nullptr, Gbuf);
  // CL = [cross | logits] = TG @ Wcg^T + bc2V   (K=2048, N=4096) -> d_out
  gemm8p_kernel<EPI_BIAS, 1><<<dim3(1024), blk, 0, stream>>>(
      TG, F, Wcg, F, F, 2 * F, 0,
      bc2V, nullptr, nullptr, CL);
  // fuse gate + residual + LN stats -> PL (=TG region), stats
  fusestats_kernel<<<dim3(Bm), dim3(256), 0, stream>>>(CL, Gbuf, PL, stats);
  // out = rstd*(preLN @ wLIN^T) - rstd*mu*u + v   (K=2048, fp32) -> d_out
  gemm8p_kernel<EPI_LNF32, 1><<<dim3(512), blk, 0, stream>>>(
      PL, F, wLIN, F, F, F, 0,
      uV, vV, stats, (void*)d_out);
}

// Round 18
// 774.323 us; speedup vs baseline: 1.0670x; 1.0085x over previous
//
#include <hip/hip_runtime.h>
#include <stdint.h>

typedef __attribute__((ext_vector_type(8))) short short8;
typedef __attribute__((ext_vector_type(4))) float f32x4;

__device__ __forceinline__ unsigned short f2bf(float f) {
  union { float f; uint32_t u; } v; v.f = f;
  uint32_t u = v.u;
  u += 0x7FFF + ((u >> 16) & 1);   // round-to-nearest-even
  return (unsigned short)(u >> 16);
}
__device__ __forceinline__ float bf2f(unsigned short h) {
  union { uint32_t u; float f; } v; v.u = ((uint32_t)h) << 16;
  return v.f;
}

// ---- concat-convert both inputs: temporal -> cols 0:1024, graph -> 1024:2048
__global__ void convcat2_kernel(const float* __restrict__ t,
                                const float* __restrict__ g,
                                unsigned short* __restrict__ out, long half) {
  long i = ((long)blockIdx.x * blockDim.x + threadIdx.x) * 8;
  const float* src;
  int colbase;
  if (i < half) { src = t; colbase = 0; }
  else { i -= half; src = g; colbase = 1024; }
  float4 a = *(const float4*)(src + i);
  float4 b = *(const float4*)(src + i + 4);
  short8 s;
  s[0] = (short)f2bf(a.x); s[1] = (short)f2bf(a.y);
  s[2] = (short)f2bf(a.z); s[3] = (short)f2bf(a.w);
  s[4] = (short)f2bf(b.x); s[5] = (short)f2bf(b.y);
  s[6] = (short)f2bf(b.z); s[7] = (short)f2bf(b.w);
  long row = i >> 10, col = i & 1023;
  *(short8*)(out + row * 2048 + colbase + col) = s;
}

// ---- 6-segment fp32->bf16 convert --------------------------------------
__global__ void multiconv6_kernel(
    const float* __restrict__ s0, unsigned short* d0, long n0,
    const float* __restrict__ s1, unsigned short* d1, long n1,
    const float* __restrict__ s2, unsigned short* d2, long n2,
    const float* __restrict__ s3, unsigned short* d3, long n3,
    const float* __restrict__ s4, unsigned short* d4, long n4,
    const float* __restrict__ s5, unsigned short* d5, long n5) {
  long i = ((long)blockIdx.x * blockDim.x + threadIdx.x) * 8;
  const float* s; unsigned short* d;
  if (i < n0) { s = s0; d = d0; }
  else if ((i -= n0) < n1) { s = s1; d = d1; }
  else if ((i -= n1) < n2) { s = s2; d = d2; }
  else if ((i -= n2) < n3) { s = s3; d = d3; }
  else if ((i -= n3) < n4) { s = s4; d = d4; }
  else { i -= n4; s = s5; d = d5; }
  float4 a = *(const float4*)(s + i);
  float4 b = *(const float4*)(s + i + 4);
  short8 o;
  o[0] = (short)f2bf(a.x); o[1] = (short)f2bf(a.y);
  o[2] = (short)f2bf(a.z); o[3] = (short)f2bf(a.w);
  o[4] = (short)f2bf(b.x); o[5] = (short)f2bf(b.y);
  o[6] = (short)f2bf(b.z); o[7] = (short)f2bf(b.w);
  *(short8*)(d + i) = o;
}

// convert with per-column scale fold: out[i] = bf16(in[i] * scale[i & 2047])
__global__ void convs_kernel(const float* __restrict__ in,
                             const float* __restrict__ scale,
                             unsigned short* __restrict__ out, int n) {
  long i = ((long)blockIdx.x * blockDim.x + threadIdx.x) * 8;
  if (i >= n) return;
  short8 s;
#pragma unroll
  for (int j = 0; j < 8; ++j)
    s[j] = (short)f2bf(in[i + j] * scale[(i + j) & 2047]);
  *(short8*)(out + i) = s;
}

// transpose-convert pair (z selects); out[C][R] = bf16(in^T)
__global__ void tconv2_kernel(const float* __restrict__ inA,
                              unsigned short* __restrict__ outA,
                              const float* __restrict__ inB,
                              unsigned short* __restrict__ outB, int R, int C) {
  const float* in = blockIdx.z ? inB : inA;
  unsigned short* out = blockIdx.z ? outB : outA;
  __shared__ float tile[32][33];
  int c0 = blockIdx.x * 32, r0 = blockIdx.y * 32;
  int tx = threadIdx.x, ty = threadIdx.y;
#pragma unroll
  for (int i = 0; i < 32; i += 8)
    tile[ty + i][tx] = in[(long)(r0 + ty + i) * C + c0 + tx];
  __syncthreads();
#pragma unroll
  for (int i = 0; i < 32; i += 8)
    out[(long)(c0 + ty + i) * R + r0 + tx] = f2bf(tile[tx][ty + i]);
}

// ---------------- 128x128 compose GEMM (r0-proven, 2-phase) ---------------
// Segments: bid < pairBase: base ptrs; [pairBase, seg2Base): base+offsets;
// >= seg2Base: (A2, lda2, W2, C2p, C2t). CE: plain / +transposed / accumulate.
enum { CE_PLAIN = 0, CE_WT = 1, CE_ACC = 2 };

template <int CE>
__global__ __launch_bounds__(256)
void compose_kernel(const unsigned short* __restrict__ A, int lda,
                    const unsigned short* __restrict__ W, int ldw,
                    unsigned short* C, int ldc,
                    unsigned short* Ct, long ctoff,
                    int K, int nmt,
                    int pairBase, long aoff, long woff, long coff,
                    int seg2Base, const unsigned short* A2, int lda2,
                    const unsigned short* W2, unsigned short* C2p,
                    unsigned short* C2t) {
  constexpr int BK = 32;
  __shared__ unsigned short sA[128 * BK];
  __shared__ unsigned short sB[128 * BK];
  const int tid  = threadIdx.x;
  const int lane = tid & 63;
  const int wave = tid >> 6;
  const int wr = (wave >> 1) * 64;
  const int wc = (wave & 1) * 64;

  int bid = blockIdx.x;
  if (bid >= seg2Base) {
    bid -= seg2Base;
    A = A2; lda = lda2; W = W2; C = C2p; Ct = C2t;
  } else if (bid >= pairBase) {
    bid -= pairBase;
    A += aoff; W += woff; C += coff; Ct += ctoff;
  }
  const long tileM = (long)(bid % nmt) * 128;
  const long tileN = (long)(bid / nmt) * 128;

  const unsigned short* gA = A + (tileM + (tid >> 2)) * (long)lda + (tid & 3) * 8;
  const unsigned short* gB = W + (tileN + (tid >> 2)) * (long)ldw + (tid & 3) * 8;
  unsigned short* lA = sA + wave * 512;
  unsigned short* lB = sB + wave * 512;

  f32x4 acc[4][4] = {};
  const int fr = lane & 15;
  const int kb = (lane >> 4) * 8;

  for (int k0 = 0; k0 < K; k0 += BK) {
    __builtin_amdgcn_global_load_lds(
        (const __attribute__((address_space(1))) void*)(gA + k0),
        (__attribute__((address_space(3))) void*)(lA), 16, 0, 0);
    __builtin_amdgcn_global_load_lds(
        (const __attribute__((address_space(1))) void*)(gA + k0 + 64 * (long)lda),
        (__attribute__((address_space(3))) void*)(lA + 2048), 16, 0, 0);
    __builtin_amdgcn_global_load_lds(
        (const __attribute__((address_space(1))) void*)(gB + k0),
        (__attribute__((address_space(3))) void*)(lB), 16, 0, 0);
    __builtin_amdgcn_global_load_lds(
        (const __attribute__((address_space(1))) void*)(gB + k0 + 64 * (long)ldw),
        (__attribute__((address_space(3))) void*)(lB + 2048), 16, 0, 0);
    __syncthreads();

    short8 aF[4], bF[4];
#pragma unroll
    for (int m = 0; m < 4; ++m)
      aF[m] = *(const short8*)&sA[(wr + m * 16 + fr) * BK + kb];
#pragma unroll
    for (int n = 0; n < 4; ++n)
      bF[n] = *(const short8*)&sB[(wc + n * 16 + fr) * BK + kb];
#pragma unroll
    for (int m = 0; m < 4; ++m)
#pragma unroll
      for (int n = 0; n < 4; ++n)
        acc[m][n] = __builtin_amdgcn_mfma_f32_16x16x32_bf16(aF[m], bF[n], acc[m][n], 0, 0, 0);
    __syncthreads();
  }

  const int cr = (lane >> 4) * 4;
  const int cc = lane & 15;
#pragma unroll
  for (int m = 0; m < 4; ++m) {
    long r0 = tileM + wr + m * 16 + cr;
#pragma unroll
    for (int n = 0; n < 4; ++n) {
      long c = tileN + wc + n * 16 + cc;
#pragma unroll
      for (int r = 0; r < 4; ++r) {
        long idx = (r0 + r) * (long)ldc + c;
        float v = acc[m][n][r];
        if constexpr (CE == CE_ACC) v += bf2f(C[idx]);
        unsigned short bv = f2bf(v);
        C[idx] = bv;
        if constexpr (CE == CE_WT) Ct[c * 2048 + (r0 + r)] = bv;
      }
    }
  }
}

// ------- 256x256 bf16 GEMM, 4 merged phases (r12-proven, 257 us CL) -------
enum { EPI_BIAS = 0, EPI_LNF32 = 4 };

#define VMW(N) asm volatile("s_waitcnt vmcnt(" #N ")" ::: "memory")
#define SBAR() __builtin_amdgcn_s_barrier()

#define STG(D, OP, HALF, PTR, LD8)                                            \
  { char* lp_ = (char*)smem + ((D)*65536 + (OP)*32768 + (HALF)*16384 + w*2048); \
    __builtin_amdgcn_global_load_lds(                                         \
        (const __attribute__((address_space(1))) void*)(PTR),                 \
        (__attribute__((address_space(3))) void*)lp_, 16, 0, 0);              \
    __builtin_amdgcn_global_load_lds(                                         \
        (const __attribute__((address_space(1))) void*)((PTR) + (LD8)),       \
        (__attribute__((address_space(3))) void*)(lp_ + 1024), 16, 0, 0);     \
    (PTR) += 64; }
#define NOSTG ((void)0)

#define RDA(D, KK) ((KK) ? ((D) ? pA11 : pA01) : ((D) ? pA10 : pA00))
#define RDB(D, KK) ((KK) ? ((D) ? pB11 : pB01) : ((D) ? pB10 : pB00))

template <int EPI, int SWZ>
__global__ __launch_bounds__(512, 2)
void gemm8p_kernel(const unsigned short* __restrict__ A, int lda,
                   const unsigned short* __restrict__ W, int ldw,
                   int K, int ldc, int nmt,
                   const float* __restrict__ bias,
                   const float* __restrict__ bias2,
                   const float2* __restrict__ stats,
                   void* Cv) {
  __shared__ unsigned short smem[65536];  // 128 KB

  const int tid = threadIdx.x, lane = tid & 63, w = tid >> 6;
  const int wm = w >> 2, wn = w & 3;

  int bid = blockIdx.x;
  int mt, nt;
  if (SWZ) {  // XCD x owns mt [x*8, x*8+8), sweeps all nt
    const int xcd = bid & 7, seq = bid >> 3;
    nt = seq >> 3;
    mt = xcd * 8 + (seq & 7);
  } else {
    mt = bid % nmt;
    nt = bid / nmt;
  }
  const long tileM = (long)mt * 256, tileN = (long)nt * 256;

  const int sRow = w * 16 + (lane >> 3);
  const int sCol = (((lane & 7) ^ ((lane >> 3) & 7)) * 8);
  const unsigned short* pSA0 = A + (tileM + sRow) * (long)lda + sCol;
  const unsigned short* pSA1 = pSA0 + 128 * (long)lda;
  const unsigned short* pSB0 = W + (tileN + sRow) * (long)ldw + sCol;
  const unsigned short* pSB1 = pSB0 + 128 * (long)ldw;
  const long lda8 = 8 * (long)lda, ldw8 = 8 * (long)ldw;

  const int fr = lane & 15, kc = lane >> 4, l7 = lane & 7;
  const char* pA00 = (const char*)smem + (wm * 16 + fr) * 128 + ((kc) ^ l7) * 16;
  const char* pA01 = (const char*)smem + (wm * 16 + fr) * 128 + ((4 + kc) ^ l7) * 16;
  const char* pA10 = pA00 + 65536;
  const char* pA11 = pA01 + 65536;
  const char* pB00 = (const char*)smem + 32768 + (wn * 16 + fr) * 128 + ((kc) ^ l7) * 16;
  const char* pB01 = (const char*)smem + 32768 + (wn * 16 + fr) * 128 + ((4 + kc) ^ l7) * 16;
  const char* pB10 = pB00 + 65536;
  const char* pB11 = pB01 + 65536;

  f32x4 acc[8][4] = {};
  short8 aH[4][2];
  short8 bqS[2][2][2];  // persists across the MQ pair of a buffer

#define MPHASE(D, MQ, LB, STGX)                                               \
  {                                                                           \
    _Pragma("unroll") for (int mi = 0; mi < 2; ++mi) {                        \
      aH[mi][0] = *(const short8*)(RDA(D, 0) + (MQ)*16384 + mi * 4096);       \
      aH[mi][1] = *(const short8*)(RDA(D, 1) + (MQ)*16384 + mi * 4096);       \
    }                                                                         \
    if (LB) {                                                                 \
      _Pragma("unroll") for (int q = 0; q < 2; ++q)                           \
      _Pragma("unroll") for (int ni = 0; ni < 2; ++ni) {                      \
        bqS[q][ni][0] = *(const short8*)(RDB(D, 0) + q * 16384 + ni * 8192);  \
        bqS[q][ni][1] = *(const short8*)(RDB(D, 1) + q * 16384 + ni * 8192);  \
      }                                                                       \
    }                                                                         \
    _Pragma("unroll") for (int mi = 2; mi < 4; ++mi) {                        \
      aH[mi][0] = *(const short8*)(RDA(D, 0) + (MQ)*16384 + mi * 4096);       \
      aH[mi][1] = *(const short8*)(RDA(D, 1) + (MQ)*16384 + mi * 4096);       \
    }                                                                         \
    STGX;                                                                     \
    __builtin_amdgcn_s_setprio(1);                                            \
    _Pragma("unroll") for (int mi = 0; mi < 4; ++mi)                          \
    _Pragma("unroll") for (int n = 0; n < 4; ++n) {                           \
      acc[(MQ)*4+mi][n] = __builtin_amdgcn_mfma_f32_16x16x32_bf16(            \
          aH[mi][0], bqS[n >> 1][n & 1][0], acc[(MQ)*4+mi][n], 0, 0, 0);      \
      acc[(MQ)*4+mi][n] = __builtin_amdgcn_mfma_f32_16x16x32_bf16(            \
          aH[mi][1], bqS[n >> 1][n & 1][1], acc[(MQ)*4+mi][n], 0, 0, 0);      \
    }                                                                         \
    __builtin_amdgcn_s_setprio(0);                                            \
  }

  // ---- prologue: d0 full + d1 {A0,B0,B1} (d1.A1 staged in MP0 of it 0) ---
  STG(0, 0, 0, pSA0, lda8);
  STG(0, 1, 0, pSB0, ldw8);
  STG(0, 1, 1, pSB1, ldw8);
  STG(0, 0, 1, pSA1, lda8);
  STG(1, 0, 0, pSA0, lda8);
  STG(1, 1, 0, pSB0, ldw8);
  STG(1, 1, 1, pSB1, ldw8);
  VMW(8);
  SBAR();

  const int NIT = K / 128;  // 2 K-tiles (BK=64) per iteration
  for (int it = 0; it < NIT - 1; ++it) {
    MPHASE(0, 0, 1, STG(1, 0, 1, pSA1, lda8));            VMW(8); SBAR();
    MPHASE(0, 1, 0, STG(0, 0, 0, pSA0, lda8);
                    STG(0, 1, 0, pSB0, ldw8);
                    STG(0, 1, 1, pSB1, ldw8));            VMW(8); SBAR();
    MPHASE(1, 0, 1, STG(0, 0, 1, pSA1, lda8));            VMW(8); SBAR();
    MPHASE(1, 1, 0, STG(1, 0, 0, pSA0, lda8);
                    STG(1, 1, 0, pSB0, ldw8);
                    STG(1, 1, 1, pSB1, ldw8));            VMW(8); SBAR();
  }
  {  // peeled drain iteration (stages only d1.A1 for the last odd tile)
    MPHASE(0, 0, 1, STG(1, 0, 1, pSA1, lda8)); VMW(8); SBAR();
    MPHASE(0, 1, 0, NOSTG);                    VMW(2); SBAR();
    MPHASE(1, 0, 1, NOSTG);                    VMW(0); SBAR();
    MPHASE(1, 1, 0, NOSTG);
  }
#undef MPHASE

  // ---- epilogue: C/D layout col = lane&15, row = (lane>>4)*4 + reg --------
  const int cr = (lane >> 4) * 4;
  const int cc = lane & 15;
#pragma unroll
  for (int m = 0; m < 8; ++m) {
    long rr = tileM + (m >> 2) * 128 + (m & 3) * 32 + wm * 16 + cr;
#pragma unroll
    for (int n = 0; n < 4; ++n) {
      long c = tileN + (n >> 1) * 128 + (n & 1) * 64 + wn * 16 + cc;
      float b1 = bias ? bias[c] : 0.0f;
      float b2 = bias2 ? bias2[c] : 0.0f;
#pragma unroll
      for (int r = 0; r < 4; ++r) {
        long row = rr + r;
        long idx = row * (long)ldc + c;
        float v = acc[m][n][r];
        if constexpr (EPI == EPI_BIAS) {
          ((unsigned short*)Cv)[idx] = f2bf(v + b1 + b2);
        }
        if constexpr (EPI == EPI_LNF32) {
          float2 st = stats[row];  // (mu, rstd)
          ((float*)Cv)[idx] = v * st.y - st.y * st.x * b1 + b2;
        }
      }
    }
  }
}

// ---- fuse gate + residual + LN stats, streaming, one row per block -------
__global__ __launch_bounds__(256) void fusestats_kernel(
    const unsigned short* __restrict__ CL, const unsigned short* __restrict__ G,
    unsigned short* __restrict__ PL, float2* __restrict__ stats) {
  const int row = blockIdx.x;
  const int t = threadIdx.x, lane = t & 63, wave = t >> 6;
  short8 xc = *(const short8*)&CL[(long)row * 4096 + t * 8];
  short8 xl = *(const short8*)&CL[(long)row * 4096 + 2048 + t * 8];
  short8 xg = *(const short8*)&G[(long)row * 2048 + t * 8];
  short8 o8;
  float s = 0.f, s2 = 0.f;
#pragma unroll
  for (int j = 0; j < 8; ++j) {
    float cv = bf2f((unsigned short)xc[j]);
    float lv = bf2f((unsigned short)xl[j]);
    float gv = bf2f((unsigned short)xg[j]);
    float gt = 1.0f / (1.0f + expf(-lv));
    unsigned short pb = f2bf(gt * gv + (1.0f - gt) * cv + gv);
    o8[j] = (short)pb;
    float x = bf2f(pb);
    s += x; s2 += x * x;
  }
  *(short8*)(PL + (long)row * 2048 + t * 8) = o8;
#pragma unroll
  for (int off = 1; off < 64; off <<= 1) {
    s  += __shfl_xor(s, off);
    s2 += __shfl_xor(s2, off);
  }
  __shared__ float red[8];
  if (lane == 0) { red[wave] = s; red[4 + wave] = s2; }
  __syncthreads();
  if (t == 0) {
    float ts  = red[0] + red[1] + red[2] + red[3];
    float ts2 = red[4] + red[5] + red[6] + red[7];
    float mean = ts * (1.0f / 2048.0f);
    float var  = ts2 * (1.0f / 2048.0f) - mean * mean;
    stats[row] = make_float2(mean, rsqrtf(var + 1e-5f));
  }
}

// block-reduce helper: 256 threads, returns total on t==0
__device__ __forceinline__ float blkRed(float s, float* red, int lane, int wave) {
#pragma unroll
  for (int off = 1; off < 64; off <<= 1) s += __shfl_xor(s, off);
  if (lane == 0) red[wave] = s;
  __syncthreads();
  return red[0] + red[1] + red[2] + red[3];
}

// qV[c] = wv1[c,:]·tp_b (c<2048)  |  qV[c] = wv2[c-2048,:]·gp_b
__global__ __launch_bounds__(256) void qvec_kernel(
    const unsigned short* __restrict__ wv1, const unsigned short* __restrict__ wv2,
    const float* __restrict__ tpb, const float* __restrict__ gpb,
    float* __restrict__ qV) {
  __shared__ float red[4];
  int bid = blockIdx.x, t = threadIdx.x, lane = t & 63, wave = t >> 6;
  const unsigned short* rowp;
  const float* bvec;
  if (bid < 2048) { rowp = wv1 + (long)bid * 2048; bvec = tpb; }
  else { rowp = wv2 + (long)(bid - 2048) * 2048; bvec = gpb; }
  int k = t * 8;
  short8 a = *(const short8*)(rowp + k);
  float s = 0.f;
#pragma unroll
  for (int j = 0; j < 8; ++j)
    s += bf2f((unsigned short)a[j]) * bvec[k + j];
  float tot = blkRed(s, red, lane, wave);
  if (t == 0) qV[bid] = tot;
}

// bcV[c] = o1b+o2b + wO1b[c]·(bv1+q1) + wO2b[c]·(bv2+q2)
__global__ __launch_bounds__(256) void biascomp2_kernel(
    const unsigned short* __restrict__ wO1b, const unsigned short* __restrict__ wO2b,
    const float* __restrict__ bv1, const float* __restrict__ bv2,
    const float* __restrict__ qV,
    const float* __restrict__ o1b, const float* __restrict__ o2b,
    float* __restrict__ bcV) {
  __shared__ float red[4];
  int c = blockIdx.x, t = threadIdx.x, lane = t & 63, wave = t >> 6;
  int k = t * 8;
  float s = 0.f;
  short8 a1 = *(const short8*)(wO1b + (long)c * 2048 + k);
  short8 a2 = *(const short8*)(wO2b + (long)c * 2048 + k);
#pragma unroll
  for (int j = 0; j < 8; ++j)
    s += bf2f((unsigned short)a1[j]) * (bv1[k + j] + qV[k + j])
       + bf2f((unsigned short)a2[j]) * (bv2[k + j] + qV[2048 + k + j]);
  float tot = blkRed(s, red, lane, wave);
  if (t == 0) bcV[c] = tot + o1b[c] + o2b[c];
}

// merged: bid<2048 -> bgateV[n] = gate_b + gw_g·gp_b + gw_c·bcV
//         bid>=2048 -> uV/vV (LN-fold vectors)
__global__ __launch_bounds__(256) void bgateuv_kernel(
    const float* __restrict__ gate_w, const float* __restrict__ gate_b,
    const float* __restrict__ gpb, const float* __restrict__ bcV,
    float* __restrict__ bgateV,
    const unsigned short* __restrict__ wlinp, const float* __restrict__ lin_w,
    const float* __restrict__ ln_beta, const float* __restrict__ lin_b,
    float* __restrict__ uV, float* __restrict__ vV) {
  __shared__ float redu[4], redv[4];
  int bid = blockIdx.x, t = threadIdx.x, lane = t & 63, wave = t >> 6;
  int k = t * 8;
  if (bid < 2048) {
    const float* row = gate_w + (long)bid * 4096;
    float s = 0.f;
#pragma unroll
    for (int j = 0; j < 8; ++j)
      s += row[k + j] * gpb[k + j] + row[2048 + k + j] * bcV[k + j];
    float tot = blkRed(s, redu, lane, wave);
    if (t == 0) bgateV[bid] = tot + gate_b[bid];
  } else {
    int n = bid - 2048;
    short8 a1 = *(const short8*)(wlinp + (long)n * 2048 + k);
    float u = 0.f, v = 0.f;
#pragma unroll
    for (int j = 0; j < 8; ++j) {
      u += bf2f((unsigned short)a1[j]);
      v += ln_beta[k + j] * lin_w[(long)n * 2048 + k + j];
    }
#pragma unroll
    for (int off = 1; off < 64; off <<= 1) {
      u += __shfl_xor(u, off);
      v += __shfl_xor(v, off);
    }
    if (lane == 0) { redu[wave] = u; redv[wave] = v; }
    __syncthreads();
    if (t == 0) {
      uV[n] = redu[0] + redu[1] + redu[2] + redu[3];
      vV[n] = redv[0] + redv[1] + redv[2] + redv[3] + lin_b[n];
    }
  }
}

// --------------------------------------------------------------------------
extern "C" void kernel_launch(void* const* d_in, const int* in_sizes, int n_in,
                              void* d_out, int out_size, void* d_ws, size_t ws_size,
                              hipStream_t stream) {
  const float* graph    = (const float*)d_in[0];
  const float* temporal = (const float*)d_in[1];
  const float* gp_w  = (const float*)d_in[2];
  const float* gp_b  = (const float*)d_in[3];
  const float* tp_w  = (const float*)d_in[4];
  const float* tp_b  = (const float*)d_in[5];
  const float* in1_w = (const float*)d_in[6];
  const float* in1_b = (const float*)d_in[7];
  const float* out1_w = (const float*)d_in[8];
  const float* out1_b = (const float*)d_in[9];
  const float* in2_w = (const float*)d_in[10];
  const float* in2_b = (const float*)d_in[11];
  const float* out2_w = (const float*)d_in[12];
  const float* out2_b = (const float*)d_in[13];
  const float* gate_w = (const float*)d_in[14];
  const float* gate_b = (const float*)d_in[15];
  const float* ln_g  = (const float*)d_in[16];
  const float* ln_b  = (const float*)d_in[17];
  const float* lin_w = (const float*)d_in[18];
  const float* lin_b = (const float*)d_in[19];

  const int Bm = 16384, F = 2048, GD = 1024;
  const long BF = (long)Bm * F, FF = (long)F * F, FG = (long)F * GD;

  // ---- ws layout (~164 MB) ----
  unsigned short* TG   = (unsigned short*)d_ws;  // [16384][2048]=[t|g]; later preLN
  unsigned short* PL   = TG;                     // preLN overwrites TG (dead)
  unsigned short* Gbuf = TG + BF;                // g
  unsigned short* wLIN = Gbuf + BF;              // gamma-folded lin_w
  unsigned short* wGP  = wLIN + FF;              // [2048][1024]
  unsigned short* Wcg  = wGP + FG;               // [4096][2048] = [Wcross; Wgate]
  unsigned short* Wcross = Wcg;
  unsigned short* Wgate  = Wcg + FF;
  float* bc2V   = (float*)(Wcg + 2 * FF);        // [4096] = [bcV | bgateV]
  float* uV     = bc2V + 2 * F;
  float* vV     = uV + F;
  float* qV     = vV + F;                        // [4096] = [q1 | q2]
  float2* stats = (float2*)(qV + 2 * F);         // 16384 float2

  // ---- d_out scratch (compose transients; ALL dead before CL GEMM) ----
  unsigned short* DO      = (unsigned short*)d_out;
  unsigned short* wv1     = DO;            // [2048][2048] (plain, not transposed)
  unsigned short* wv2     = wv1 + FF;
  unsigned short* tpT     = wv2 + FF;      // [1024][2048]
  unsigned short* gpT     = tpT + FG;
  unsigned short* wO1b    = gpT + FG;      // [2048][2048]
  unsigned short* wO2b    = wO1b + FF;
  unsigned short* wGATEb  = wO2b + FF;     // [2048][4096]
  unsigned short* P1      = wGATEb + 2 * FF;  // [2048][1024]
  unsigned short* P2      = P1 + FG;
  unsigned short* P1T     = P2 + FG;       // [1024][2048]
  unsigned short* P2T     = P1T + FG;
  unsigned short* WcrossT = P2T + FG;      // [2048][2048]
  unsigned short* Ctscr   = WcrossT + FF;  // [1024][2048] (seg3 WT dump)
  unsigned short* CL      = DO;            // [16384][4096] — overwrites all above

  // 1) zero Wgate (W-pair seg3 writes g-cols; C3 accumulates full width)
  hipMemsetAsync(Wgate, 0, FF * sizeof(unsigned short), stream);
  // 2) inputs -> TG = [temporal | graph]
  convcat2_kernel<<<dim3((unsigned)(2 * Bm * GD / 8 / 256)), 256, 0, stream>>>(
      temporal, graph, TG, (long)Bm * GD);
  // 3) weight converts (one kernel, 6 segments; wv1/wv2 now PLAIN)
  {
    long ntot = FG + 4 * FF + 2 * FF;
    multiconv6_kernel<<<dim3((unsigned)(ntot / 8 / 256)), 256, 0, stream>>>(
        gp_w, wGP, FG, out1_w, wO1b, FF, out2_w, wO2b, FF,
        gate_w, wGATEb, 2 * FF,
        in1_w + 2 * FF, wv1, FF, in2_w + 2 * FF, wv2, FF);
  }
  // 4) gamma-folded lin_w
  convs_kernel<<<dim3((unsigned)(FF / 8 / 256)), 256, 0, stream>>>(lin_w, ln_g, wLIN, (int)FF);
  // 5) transposes (tp_w, gp_w only)
  tconv2_kernel<<<dim3(GD / 32, F / 32, 2), dim3(32, 8), 0, stream>>>(
      tp_w, tpT, gp_w, gpT, F, GD);

  // 6) P-pair (256 blocks): P1 = wv1@tp_w, P2 = wv2@gp_w  [2048,1024] + P^T
  compose_kernel<CE_WT><<<dim3(256), dim3(256), 0, stream>>>(
      wv1, F, tpT, F, P1, GD, P1T, P2T - P1T, F, 16,
      128, wv2 - wv1, gpT - tpT, P2 - P1,
      1 << 30, nullptr, 0, nullptr, nullptr, nullptr);
  // 7) q vectors (needs wv1/wv2)
  qvec_kernel<<<dim3(2 * F), dim3(256), 0, stream>>>(wv1, wv2, tp_b, gp_b, qV);
  // 8) W-pair + seg3 (384 blocks):
  //    Wcross[:,0:1024] = wO1@P1 | Wcross[:,1024:] = wO2@P2 (pair) + WcrossT
  //    seg3: Wgate[:,1024:] = gw_g@gp_w  (WT dump -> Ctscr)
  compose_kernel<CE_WT><<<dim3(384), dim3(256), 0, stream>>>(
      wO1b, F, P1T, F, Wcross, F, WcrossT, (long)1024 * 2048, F, 16,
      128, wO2b - wO1b, P2T - P1T, 1024,
      256, wGATEb, 2 * F, gpT, Wgate + GD, Ctscr);
  // 9) composed cross-bias (re-associated via q)
  biascomp2_kernel<<<dim3(F), dim3(256), 0, stream>>>(
      wO1b, wO2b, in1_b + 2 * F, in2_b + 2 * F, qV, out1_b, out2_b, bc2V);
  // 10) gate bias + LN-fold vectors (merged)
  bgateuv_kernel<<<dim3(2 * F), dim3(256), 0, stream>>>(
      gate_w, gate_b, gp_b, bc2V, bc2V + F,
      wLIN, lin_w, ln_b, lin_b, uV, vV);
  // 11) C3: Wgate += gw_c @ Wcross
  compose_kernel<CE_ACC><<<dim3(256), dim3(256), 0, stream>>>(
      wGATEb + F, 2 * F, WcrossT, F, Wgate, F, nullptr, 0, F, 16,
      1 << 30, 0, 0, 0,
      1 << 30, nullptr, 0, nullptr, nullptr, nullptr);

  dim3 blk(512);
  // g = graph @ gp_w^T + gp_b          (K=1024) -> Gbuf
  gemm8p_kernel<EPI_BIAS, 1><<<dim3(512), blk, 0, stream>>>(
      TG + GD, F, wGP, GD, GD, F, 0,
      gp_b, nullptr, nullptr, Gbuf);
  // CL = [cross | logits] = TG @ Wcg^T + bc2V   (K=2048, N=4096) -> d_out
  gemm8p_kernel<EPI_BIAS, 1><<<dim3(1024), blk, 0, stream>>>(
      TG, F, Wcg, F, F, 2 * F, 0,
      bc2V, nullptr, nullptr, CL);
  // fuse gate + residual + LN stats -> PL (=TG region), stats
  fusestats_kernel<<<dim3(Bm), dim3(256), 0, stream>>>(CL, Gbuf, PL, stats);
  // out = rstd*(preLN @ wLIN^T) - rstd*mu*u + v   (K=2048, fp32) -> d_out
  gemm8p_kernel<EPI_LNF32, 1><<<dim3(512), blk, 0, stream>>>(
      PL, F, wLIN, F, F, F, 0,
      uV, vV, stats, (void*)d_out);
}